// Round 2
// baseline (689.370 us; speedup 1.0000x reference)
//
#include <hip/hip_runtime.h>

#define NB   16
#define NN   2048
#define NPTS (NB * NN)
#define KNB  6

typedef __attribute__((ext_vector_type(8))) short short8;
typedef __attribute__((ext_vector_type(4))) float f32x4;
typedef const __attribute__((address_space(4))) float cfloat;

// ---------------- split-precision + squared-norm fused prep ----------------
__device__ __forceinline__ unsigned bf16_rne(float f) {
    unsigned u = __float_as_uint(f);
    return (u + 0x7fffu + ((u >> 16) & 1u)) >> 16;
}

template<int C>
__global__ void prep_fused(const float* __restrict__ x,
                           unsigned short* __restrict__ Xhi,
                           unsigned short* __restrict__ Xlo,
                           float* __restrict__ sq) {
    int i = blockIdx.x * 256 + threadIdx.x;
    if (i >= NPTS) return;
    const float4* r = (const float4*)(x + (size_t)i * C);
    float s = 0.f;
#pragma unroll
    for (int cc = 0; cc < C; cc += 8) {
        float4 f0 = r[cc / 4 + 0];
        float4 f1 = r[cc / 4 + 1];
        const float fs[8] = {f0.x, f0.y, f0.z, f0.w, f1.x, f1.y, f1.z, f1.w};
        short8 vh, vl;
#pragma unroll
        for (int t = 0; t < 8; ++t) {
            const float f = fs[t];
            s = fmaf(f, f, s);
            const unsigned h = bf16_rne(f);
            const float hf = __uint_as_float(h << 16);
            const unsigned l = bf16_rne(f - hf);
            vh[t] = (short)h;
            vl[t] = (short)l;
        }
        *(short8*)(Xhi + (size_t)i * C + cc) = vh;
        *(short8*)(Xlo + (size_t)i * C + cc) = vl;
    }
    sq[i] = s;
}

// ---------------- weight prep: transpose the three W1s ----------------
__global__ void prep_w(const float* __restrict__ W10, const float* __restrict__ W11,
                       const float* __restrict__ W12,
                       float* __restrict__ T0, float* __restrict__ T1,
                       float* __restrict__ T2) {
    int t = blockIdx.x * 256 + threadIdx.x;
    if (t < 4096) { int o = t >> 6, c = t & 63;  T0[o * 64 + c]  = W10[c * 64 + o]; }
    if (t < 4096) { int o = t >> 7, c = t & 127; T1[o * 128 + c] = W11[c * 32 + o]; }
    if (t < 4096) { int o = t >> 6, c = t & 63;  T2[o * 64 + c]  = W12[c * 64 + o]; }
}

// sorted ascending top-6 insert via pure min/max network (2 VALU / level).
__device__ __forceinline__ void insert6f(float s, float* dl) {
#pragma unroll
    for (int k = 0; k < 6; ++k) {
        const float a = dl[k];
        dl[k] = fminf(s, a);
        s = fmaxf(s, a);
    }
}

// ---------------- MFMA kNN scan ----------------
// wave = 16 queries x 512 candidates (quarter sp of the batch).
// 4-way candidate split -> 2048 blocks = 8 blocks/CU = 32 waves/CU (100% occ)
// for latency hiding. XCD swizzle: 256 consecutive (swizzled) blocks per XCD
// = 2 complete batches = <=1MB candidate set, fits the 4MB per-XCD L2.
// Selection trick: candidate id within a lane's (sp,g) sublist needs only
// 8 bits (7 used: block-of-16 index * 4 + row), OR'ed into the low mantissa
// bits of the approx score (perturbation <= 2^-15 rel; superset-of-8 + exact
// rescore tolerates far more). Top-6 maintenance = pure float min/max net.
// plist entries are sortable-transformed u32; jloc is decoded in rescore.
template<int C>
__global__ __launch_bounds__(256, 8)
void knn_scan(const unsigned short* __restrict__ Xhi,
              const unsigned short* __restrict__ Xlo,
              const float* __restrict__ sqv,
              unsigned* __restrict__ plist) {
    constexpr int KT = C / 32;
    const int w    = __builtin_amdgcn_readfirstlane(threadIdx.x >> 6);
    const int bid  = blockIdx.x;
    const int swz  = ((bid & 7) << 8) | (bid >> 3);   // XCD-chunked, bijective (2048 % 8 == 0)
    const int W    = swz * 4 + w;
    const int sp   = W & 3;                 // candidate quarter
    const int qt   = (W >> 2) & 127;        // query tile
    const int b    = W >> 9;                // batch
    const int lane = threadIdx.x & 63;
    const int n    = lane & 15;             // query within tile (D col)
    const int g    = lane >> 4;             // row group (D rows 4g..4g+3)
    const int base = b * NN;
    const int qloc = qt * 16 + n;           // batch-local query index

    // B fragments (queries), persistent: KT tiles x {hi,lo}
    short8 bh[KT], bl[KT];
#pragma unroll
    for (int kt = 0; kt < KT; ++kt) {
        const size_t off = (size_t)(base + qloc) * C + kt * 32 + g * 8;
        bh[kt] = *(const short8*)(Xhi + off);
        bl[kt] = *(const short8*)(Xlo + off);
    }

    float dl[6];
#pragma unroll
    for (int k = 0; k < 6; ++k) dl[k] = 1e30f;

    const int jbeg   = sp * (NN / 4);
    const int jend   = jbeg + NN / 4;
    const int selfjb = qt * 16;             // the only block that can contain self

    short8 ah0[KT], al0[KT], ah1[KT], al1[KT];
    float4 q0, q1;

#define LOADA(AH, AL, Q, JB) do {                                              \
    _Pragma("unroll")                                                          \
    for (int kt = 0; kt < KT; ++kt) {                                          \
        const size_t off = (size_t)(base + (JB) + n) * C + kt * 32 + g * 8;    \
        AH[kt] = *(const short8*)(Xhi + off);                                  \
        AL[kt] = *(const short8*)(Xlo + off);                                  \
    }                                                                          \
    Q = *(const float4*)(sqv + base + (JB) + g * 4);                           \
} while (0)

#define PROC(AH, AL, Q, JB) do {                                               \
    f32x4 acc = {0.f, 0.f, 0.f, 0.f};                                          \
    _Pragma("unroll")                                                          \
    for (int kt = 0; kt < KT; ++kt) {                                          \
        acc = __builtin_amdgcn_mfma_f32_16x16x32_bf16(AH[kt], bh[kt], acc, 0, 0, 0); \
        acc = __builtin_amdgcn_mfma_f32_16x16x32_bf16(AH[kt], bl[kt], acc, 0, 0, 0); \
        acc = __builtin_amdgcn_mfma_f32_16x16x32_bf16(AL[kt], bh[kt], acc, 0, 0, 0); \
    }                                                                          \
    const unsigned eb = (unsigned)(((JB) - jbeg) >> 2);                        \
    float sc0 = fmaf(-2.f, acc[0], Q.x);                                       \
    float sc1 = fmaf(-2.f, acc[1], Q.y);                                       \
    float sc2 = fmaf(-2.f, acc[2], Q.z);                                       \
    float sc3 = fmaf(-2.f, acc[3], Q.w);                                       \
    sc0 = __uint_as_float((__float_as_uint(sc0) & 0xFFFFFF00u) | (eb + 0u));   \
    sc1 = __uint_as_float((__float_as_uint(sc1) & 0xFFFFFF00u) | (eb + 1u));   \
    sc2 = __uint_as_float((__float_as_uint(sc2) & 0xFFFFFF00u) | (eb + 2u));   \
    sc3 = __uint_as_float((__float_as_uint(sc3) & 0xFFFFFF00u) | (eb + 3u));   \
    if ((JB) == selfjb) {                   /* wave-uniform branch */          \
        const int j0 = (JB) + g * 4;                                           \
        sc0 = (j0 + 0 == qloc) ? 1e30f : sc0;                                  \
        sc1 = (j0 + 1 == qloc) ? 1e30f : sc1;                                  \
        sc2 = (j0 + 2 == qloc) ? 1e30f : sc2;                                  \
        sc3 = (j0 + 3 == qloc) ? 1e30f : sc3;                                  \
    }                                                                          \
    insert6f(sc0, dl);                                                         \
    insert6f(sc1, dl);                                                         \
    insert6f(sc2, dl);                                                         \
    insert6f(sc3, dl);                                                         \
} while (0)

    LOADA(ah0, al0, q0, jbeg);
    for (int jb = jbeg; jb < jend; jb += 32) {
        LOADA(ah1, al1, q1, jb + 16);
        PROC(ah0, al0, q0, jb);
        const int jn = (jb + 32 < jend) ? jb + 32 : jbeg;   // clamped prefetch
        LOADA(ah0, al0, q0, jn);
        PROC(ah1, al1, q1, jb + 16);
    }
#undef LOADA
#undef PROC

    // write this lane's sorted sublist as sortable-transformed u32 keys
    // (index stays embedded in the low 8 bits; decoded in rescore).
    unsigned* o = plist + (size_t)(base + qloc) * 96 + (sp * 4 + g) * 6;
#pragma unroll
    for (int k = 0; k < 6; ++k) {
        const unsigned bits = __float_as_uint(dl[k]);
        o[k] = bits ^ ((bits & 0x80000000u) ? 0xFFFFFFFFu : 0x80000000u);
    }
}

// ---------------- exact rescore: approx top-8 -> exact fp32 top-6 ----------------
// thread = query. Merge 16 sorted 6-sublists (u32 keys tagged with 4-bit z)
// -> approx-best 8 candidates (superset of exact top-6), recompute their
// scores in exact fp32, pick exact top-6 with exact (dist, index) tie-break.
template<int C>
__global__ __launch_bounds__(256)
void rescore(const float* __restrict__ x, const float* __restrict__ sqv,
             const unsigned* __restrict__ plist, int* __restrict__ nbr) {
    const int i = blockIdx.x * 256 + threadIdx.x;
    if (i >= NPTS) return;
    const unsigned* pr = plist + (size_t)i * 96;

    unsigned long long best[8];
#pragma unroll
    for (int k = 0; k < 8; ++k) best[k] = ~0ull;
    for (int z = 0; z < 16; ++z) {
        const unsigned* p = pr + z * 6;
        for (int e = 0; e < 6; ++e) {
            unsigned long long v = ((unsigned long long)p[e] << 4) | (unsigned)z;
            if (v >= best[7]) break;      // sublist ascending
            best[7] = v;
#pragma unroll
            for (int k = 6; k >= 0; --k) {
                if (best[k + 1] < best[k]) {
                    unsigned long long t = best[k]; best[k] = best[k + 1]; best[k + 1] = t;
                }
            }
        }
    }

    const int base = i & ~(NN - 1);
    // query row in registers
    float4 qv[C / 4];
    const float4* qp = (const float4*)(x + (size_t)i * C);
#pragma unroll
    for (int t = 0; t < C / 4; ++t) qv[t] = qp[t];

    unsigned long long out6[6];
#pragma unroll
    for (int k = 0; k < 6; ++k) out6[k] = ~0ull;

    for (int m = 0; m < 8; ++m) {
        // decode (z, embedded e-bits) -> batch-local candidate index
        const unsigned u32k = (unsigned)(best[m] >> 4);
        const int z = (int)(best[m] & 15ull);
        const unsigned orig = (u32k & 0x80000000u) ? (u32k ^ 0x80000000u) : ~u32k;
        const int e = (int)(orig & 255u);
        const int jloc = (z >> 2) * (NN / 4) + ((e & 0xFC) << 2) + (z & 3) * 4 + (e & 3);

        const float4* cp = (const float4*)(x + (size_t)(base + jloc) * C);
        float d0 = 0.f, d1 = 0.f, d2 = 0.f, d3 = 0.f;
#pragma unroll
        for (int t = 0; t < C / 4; ++t) {
            float4 a = cp[t];
            d0 = fmaf(a.x, qv[t].x, d0);
            d1 = fmaf(a.y, qv[t].y, d1);
            d2 = fmaf(a.z, qv[t].z, d2);
            d3 = fmaf(a.w, qv[t].w, d3);
        }
        const float s = fmaf(-2.f, (d0 + d1) + (d2 + d3), sqv[base + jloc]);
        unsigned u = __float_as_uint(s);
        u ^= (u & 0x80000000u) ? 0xFFFFFFFFu : 0x80000000u;
        unsigned long long key = ((unsigned long long)u << 11) | (unsigned)jloc;
#pragma unroll
        for (int k = 0; k < 6; ++k) {
            const unsigned long long ok = out6[k];
            const bool c = key < ok;
            out6[k] = c ? key : ok;
            key     = c ? ok  : key;
        }
    }
#pragma unroll
    for (int k = 0; k < 6; ++k)
        nbr[i * KNB + k] = base + (int)(out6[k] & 2047ull);
}

// ---------------- edge MLP kernel ----------------
template<int CIN, int COUT, bool RESID, int MINW>
__global__ __launch_bounds__(384, MINW)
void mlp_kernel(const float* __restrict__ xin, const int* __restrict__ nbr,
                const float* __restrict__ W1T, const float* __restrict__ b1,
                const float* __restrict__ W2,  const float* __restrict__ b2,
                const float* __restrict__ resid, float* __restrict__ out) {
    constexpr int RS = COUT + 4;
    __shared__ float Buf[3][64][RS];

    const int lane = threadIdx.x & 63;
    const int w    = __builtin_amdgcn_readfirstlane(threadIdx.x >> 6);  // 0..5
    const int i    = blockIdx.x * 64 + lane;

    float xi[CIN], xd[CIN];
    {
        const float* xp = xin + (size_t)i * CIN;
#pragma unroll
        for (int c = 0; c < CIN; c += 4) {
            float4 f = *(const float4*)(xp + c);
            xi[c] = f.x; xi[c + 1] = f.y; xi[c + 2] = f.z; xi[c + 3] = f.w;
        }
        const int j = nbr[i * KNB + w];
        const float* jp = xin + (size_t)j * CIN;
#pragma unroll
        for (int c = 0; c < CIN; c += 4) {
            float4 f = *(const float4*)(jp + c);
            xd[c]     = f.x - xi[c];     xd[c + 1] = f.y - xi[c + 1];
            xd[c + 2] = f.z - xi[c + 2]; xd[c + 3] = f.w - xi[c + 3];
        }
    }

    float uacc[COUT];
#pragma unroll
    for (int o = 0; o < COUT; ++o) uacc[o] = 0.f;

    cfloat* W1c = (cfloat*)(uintptr_t)W1T;
    cfloat* b1c = (cfloat*)(uintptr_t)b1;
    cfloat* W2c = (cfloat*)(uintptr_t)W2;

    for (int op = 0; op < COUT; ++op) {
        cfloat* w1r = W1c + (size_t)op * (2 * CIN);
        float h0 = 0.f, h1 = 0.f, h2 = 0.f, h3 = 0.f;
#pragma unroll
        for (int c = 0; c < CIN; c += 4) {
            h0 = fmaf(w1r[c],     xi[c],     h0);
            h1 = fmaf(w1r[c + 1], xi[c + 1], h1);
            h2 = fmaf(w1r[c + 2], xi[c + 2], h2);
            h3 = fmaf(w1r[c + 3], xi[c + 3], h3);
        }
#pragma unroll
        for (int c = 0; c < CIN; c += 4) {
            h0 = fmaf(w1r[CIN + c],     xd[c],     h0);
            h1 = fmaf(w1r[CIN + c + 1], xd[c + 1], h1);
            h2 = fmaf(w1r[CIN + c + 2], xd[c + 2], h2);
            h3 = fmaf(w1r[CIN + c + 3], xd[c + 3], h3);
        }
        const float h = fmaxf((h0 + h1) + (h2 + h3) + b1c[op], 0.f);
        cfloat* w2r = W2c + (size_t)op * COUT;
#pragma unroll
        for (int o = 0; o < COUT; ++o)
            uacc[o] = fmaf(w2r[o], h, uacc[o]);
    }

    if (w >= 3) {
#pragma unroll
        for (int o = 0; o < COUT; ++o) Buf[w - 3][lane][o] = uacc[o];
    }
    __syncthreads();
    if (w < 3) {
#pragma unroll
        for (int o = 0; o < COUT; ++o) uacc[o] = fmaxf(uacc[o], Buf[w][lane][o]);
    }
    __syncthreads();
    if (w == 1 || w == 2) {
#pragma unroll
        for (int o = 0; o < COUT; ++o) Buf[w][lane][o] = uacc[o];
    }
    __syncthreads();
    if (w == 0) {
        float* po = out + (size_t)i * COUT;
#pragma unroll
        for (int o = 0; o < COUT; ++o) {
            float v = fmaxf(uacc[o], fmaxf(Buf[1][lane][o], Buf[2][lane][o])) + b2[o];
            if (RESID) v += resid[(size_t)i * COUT + o];
            po[o] = fmaxf(v, 0.f);
        }
    }
}

extern "C" void kernel_launch(void* const* d_in, const int* in_sizes, int n_in,
                              void* d_out, int out_size, void* d_ws, size_t ws_size,
                              hipStream_t stream) {
    const float* x    = (const float*)d_in[0];
    const float* W1_0 = (const float*)d_in[2];
    const float* b1_0 = (const float*)d_in[3];
    const float* W2_0 = (const float*)d_in[4];
    const float* b2_0 = (const float*)d_in[5];
    const float* W1_1 = (const float*)d_in[6];
    const float* b1_1 = (const float*)d_in[7];
    const float* W2_1 = (const float*)d_in[8];
    const float* b2_1 = (const float*)d_in[9];
    const float* W1_2 = (const float*)d_in[10];
    const float* b1_2 = (const float*)d_in[11];
    const float* W2_2 = (const float*)d_in[12];
    const float* b2_2 = (const float*)d_in[13];
    float* outp = (float*)d_out;

    // workspace layout (same byte budget as before: 96 u32 == 48 u64 per point)
    unsigned* plist = (unsigned*)d_ws;                            // NPTS*96 u32
    float* x0  = (float*)(plist + (size_t)NPTS * 96);             // 32768 x 64
    float* x1  = x0 + (size_t)NPTS * 64;                          // 32768 x 32
    float* sqb = x1 + (size_t)NPTS * 32;                          // 32768
    float* T0  = sqb + NPTS;                                      // 64 x 64
    float* T1  = T0 + 4096;                                       // 32 x 128
    float* T2  = T1 + 4096;                                       // 64 x 64
    unsigned short* Xhi = (unsigned short*)(T2 + 4096);           // 32768 x 64 u16
    unsigned short* Xlo = Xhi + (size_t)NPTS * 64;                // 32768 x 64 u16
    int* nbr = (int*)(Xlo + (size_t)NPTS * 64);                   // 32768 x 6

    const int sgrid  = NPTS / 256;
    const int scgrid = 2048;            // 8192 waves -> 32 waves/CU
    const int pgrid  = NPTS / 64;

    prep_w<<<16, 256, 0, stream>>>(W1_0, W1_1, W1_2, T0, T1, T2);

    // ---- layer 0: x (32) -> x0 (64), relu ----
    prep_fused<32><<<sgrid, 256, 0, stream>>>(x, Xhi, Xlo, sqb);
    knn_scan<32><<<scgrid, 256, 0, stream>>>(Xhi, Xlo, sqb, plist);
    rescore<32><<<sgrid, 256, 0, stream>>>(x, sqb, plist, nbr);
    mlp_kernel<32, 64, false, 3><<<pgrid, 384, 0, stream>>>(x, nbr, T0, b1_0, W2_0, b2_0, nullptr, x0);

    // ---- layer 1: x0 (64) -> x1 (32), relu ----
    prep_fused<64><<<sgrid, 256, 0, stream>>>(x0, Xhi, Xlo, sqb);
    knn_scan<64><<<scgrid, 256, 0, stream>>>(Xhi, Xlo, sqb, plist);
    rescore<64><<<sgrid, 256, 0, stream>>>(x0, sqb, plist, nbr);
    mlp_kernel<64, 32, false, 2><<<pgrid, 384, 0, stream>>>(x0, nbr, T1, b1_1, W2_1, b2_1, nullptr, x1);

    // ---- layer 2: x1 (32) -> out (64), +x0 residual, relu ----
    prep_fused<32><<<sgrid, 256, 0, stream>>>(x1, Xhi, Xlo, sqb);
    knn_scan<32><<<scgrid, 256, 0, stream>>>(Xhi, Xlo, sqb, plist);
    rescore<32><<<sgrid, 256, 0, stream>>>(x1, sqb, plist, nbr);
    mlp_kernel<32, 64, true, 3><<<pgrid, 384, 0, stream>>>(x1, nbr, T2, b1_2, W2_2, b2_2, x0, outp);
}

// Round 3
// 605.571 us; speedup vs baseline: 1.1384x; 1.1384x over previous
//
#include <hip/hip_runtime.h>

#define NB   16
#define NN   2048
#define NPTS (NB * NN)
#define KNB  6

typedef __attribute__((ext_vector_type(8))) short short8;
typedef __attribute__((ext_vector_type(4))) float f32x4;
typedef __attribute__((ext_vector_type(16))) float f32x16;
typedef const __attribute__((address_space(4))) float cfloat;

// ---------------- split-precision + squared-norm fused prep ----------------
__device__ __forceinline__ unsigned bf16_rne(float f) {
    unsigned u = __float_as_uint(f);
    return (u + 0x7fffu + ((u >> 16) & 1u)) >> 16;
}

template<int C>
__global__ void prep_fused(const float* __restrict__ x,
                           unsigned short* __restrict__ Xhi,
                           unsigned short* __restrict__ Xlo,
                           float* __restrict__ sq) {
    int i = blockIdx.x * 256 + threadIdx.x;
    if (i >= NPTS) return;
    const float4* r = (const float4*)(x + (size_t)i * C);
    float s = 0.f;
#pragma unroll
    for (int cc = 0; cc < C; cc += 8) {
        float4 f0 = r[cc / 4 + 0];
        float4 f1 = r[cc / 4 + 1];
        const float fs[8] = {f0.x, f0.y, f0.z, f0.w, f1.x, f1.y, f1.z, f1.w};
        short8 vh, vl;
#pragma unroll
        for (int t = 0; t < 8; ++t) {
            const float f = fs[t];
            s = fmaf(f, f, s);
            const unsigned h = bf16_rne(f);
            const float hf = __uint_as_float(h << 16);
            const unsigned l = bf16_rne(f - hf);
            vh[t] = (short)h;
            vl[t] = (short)l;
        }
        *(short8*)(Xhi + (size_t)i * C + cc) = vh;
        *(short8*)(Xlo + (size_t)i * C + cc) = vl;
    }
    sq[i] = s;
}

// ---------------- weight prep: transpose the three W1s ----------------
__global__ void prep_w(const float* __restrict__ W10, const float* __restrict__ W11,
                       const float* __restrict__ W12,
                       float* __restrict__ T0, float* __restrict__ T1,
                       float* __restrict__ T2) {
    int t = blockIdx.x * 256 + threadIdx.x;
    if (t < 4096) { int o = t >> 6, c = t & 63;  T0[o * 64 + c]  = W10[c * 64 + o]; }
    if (t < 4096) { int o = t >> 7, c = t & 127; T1[o * 128 + c] = W11[c * 32 + o]; }
    if (t < 4096) { int o = t >> 6, c = t & 63;  T2[o * 64 + c]  = W12[c * 64 + o]; }
}

// sorted ascending top-6 insert via pure min/max network (2 VALU / level).
__device__ __forceinline__ void insert6f(float s, float* dl) {
#pragma unroll
    for (int k = 0; k < 6; ++k) {
        const float a = dl[k];
        dl[k] = fminf(s, a);
        s = fmaxf(s, a);
    }
}

// ---------------- MFMA kNN scan (32x32 tiles) ----------------
// wave = 32 queries x 512 candidates (quarter sp). MFMA 32x32x16 bf16 with
// hi/lo split (hh + hl + lh): one step = 32 cands x 32 queries -> 4x fewer
// wave-steps / VMEM instrs / waitcnts than the 16x16 version (R0-R2 showed
// time pinned to step count, not bytes/VALU/occupancy).
// Block = 4 waves sharing (batch b, quarter sp), differing in query tile ->
// all 16 waves on a CU stream identical candidate lines (L1 reuse).
// A = candidates (row = lane&31), B = queries (col = lane&31),
// C/D: col = lane&31 (query), row = (reg&3) + 8*(reg>>2) + 4*(lane>>5).
// Embed: e = step*16 + (r&3) + 4*(r>>2) (8 bits) in score low mantissa;
// sublist z = sp*2 + (lane>>5); decode in rescore.
template<int C, int MINW>
__global__ __launch_bounds__(256, MINW)
void knn_scan(const unsigned short* __restrict__ Xhi,
              const unsigned short* __restrict__ Xlo,
              const float* __restrict__ sqv,
              unsigned* __restrict__ plist) {
    constexpr int KT = C / 16;              // K=16 tiles per product
    const int w    = __builtin_amdgcn_readfirstlane(threadIdx.x >> 6);
    const int bid  = blockIdx.x;
    const int swz  = ((bid & 7) << 7) | (bid >> 3);   // 1024 blocks, 128/XCD
    const int b    = swz >> 6;              // batch (2 per XCD)
    const int sp   = (swz >> 4) & 3;        // candidate quarter
    const int qg   = swz & 15;              // query group of 4 tiles
    const int qt   = qg * 4 + w;            // this wave's query tile (32 q)
    const int lane = threadIdx.x & 63;
    const int q31  = lane & 31;
    const int lh   = lane >> 5;
    const int base = b * NN;
    const int qloc = qt * 32 + q31;         // batch-local query index

    // B fragments (queries), persistent: KT tiles x {hi,lo}
    short8 bh[KT], bl[KT];
#pragma unroll
    for (int kt = 0; kt < KT; ++kt) {
        const size_t off = (size_t)(base + qloc) * C + kt * 16 + lh * 8;
        bh[kt] = *(const short8*)(Xhi + off);
        bl[kt] = *(const short8*)(Xlo + off);
    }

    float dl[6];
#pragma unroll
    for (int k = 0; k < 6; ++k) dl[k] = 1e30f;

    const int jbeg   = sp * (NN / 4);
    const int jend   = jbeg + NN / 4;
    const int selfjb = qt * 32;             // only block that can contain self

    short8 ah0[KT], al0[KT], ah1[KT], al1[KT];

#define LOADA(AH, AL, JB) do {                                                 \
    _Pragma("unroll")                                                          \
    for (int kt = 0; kt < KT; ++kt) {                                          \
        const size_t off = (size_t)(base + (JB) + q31) * C + kt * 16 + lh * 8; \
        AH[kt] = *(const short8*)(Xhi + off);                                  \
        AL[kt] = *(const short8*)(Xlo + off);                                  \
    }                                                                          \
} while (0)

#define PROC(AH, AL, JB) do {                                                  \
    f32x16 acc = {0.f};                                                        \
    _Pragma("unroll")                                                          \
    for (int kt = 0; kt < KT; ++kt) {                                          \
        acc = __builtin_amdgcn_mfma_f32_32x32x16_bf16(AH[kt], bh[kt], acc, 0, 0, 0); \
        acc = __builtin_amdgcn_mfma_f32_32x32x16_bf16(AH[kt], bl[kt], acc, 0, 0, 0); \
        acc = __builtin_amdgcn_mfma_f32_32x32x16_bf16(AL[kt], bh[kt], acc, 0, 0, 0); \
    }                                                                          \
    float4 s40 = *(const float4*)(sqv + base + (JB) + lh * 4);                 \
    float4 s41 = *(const float4*)(sqv + base + (JB) + lh * 4 + 8);             \
    float4 s42 = *(const float4*)(sqv + base + (JB) + lh * 4 + 16);            \
    float4 s43 = *(const float4*)(sqv + base + (JB) + lh * 4 + 24);            \
    const float sqr[16] = {s40.x, s40.y, s40.z, s40.w, s41.x, s41.y, s41.z, s41.w, \
                           s42.x, s42.y, s42.z, s42.w, s43.x, s43.y, s43.z, s43.w}; \
    const unsigned ebase = (unsigned)(((JB) - jbeg) >> 1);   /* step*16 */     \
    const bool selfstep = ((JB) == selfjb);                                    \
    _Pragma("unroll")                                                          \
    for (int r = 0; r < 16; ++r) {                                             \
        float sc = fmaf(-2.f, acc[r], sqr[r]);                                 \
        sc = __uint_as_float((__float_as_uint(sc) & 0xFFFFFF00u) |             \
                             (ebase + (unsigned)((r & 3) + 4 * (r >> 2))));    \
        if (selfstep) {                                                        \
            const int rowr = (r & 3) + 8 * (r >> 2) + 4 * lh;                  \
            sc = (rowr == q31) ? 1e30f : sc;                                   \
        }                                                                      \
        insert6f(sc, dl);                                                      \
    }                                                                          \
} while (0)

    LOADA(ah0, al0, jbeg);
    for (int jb = jbeg; jb < jend; jb += 64) {
        LOADA(ah1, al1, jb + 32);
        PROC(ah0, al0, jb);
        const int jn = (jb + 64 < jend) ? jb + 64 : jbeg;   // clamped prefetch
        LOADA(ah0, al0, jn);
        PROC(ah1, al1, jb + 32);
    }
#undef LOADA
#undef PROC

    // write this lane's sorted sublist as sortable-transformed u32 keys
    // (candidate id stays embedded in the low 8 bits; decoded in rescore).
    unsigned* o = plist + (size_t)(base + qloc) * 48 + (sp * 2 + lh) * 6;
#pragma unroll
    for (int k = 0; k < 6; ++k) {
        const unsigned bits = __float_as_uint(dl[k]);
        o[k] = bits ^ ((bits & 0x80000000u) ? 0xFFFFFFFFu : 0x80000000u);
    }
}

// ---------------- exact rescore: approx top-8 -> exact fp32 top-6 ----------------
// thread = query. Merge 8 sorted 6-sublists (u32 keys tagged with 3-bit z)
// -> approx-best 8 candidates (superset of exact top-6), recompute their
// scores in exact fp32, pick exact top-6 with exact (dist, index) tie-break.
template<int C>
__global__ __launch_bounds__(256)
void rescore(const float* __restrict__ x, const float* __restrict__ sqv,
             const unsigned* __restrict__ plist, int* __restrict__ nbr) {
    const int i = blockIdx.x * 256 + threadIdx.x;
    if (i >= NPTS) return;
    const unsigned* pr = plist + (size_t)i * 48;

    unsigned long long best[8];
#pragma unroll
    for (int k = 0; k < 8; ++k) best[k] = ~0ull;
    for (int z = 0; z < 8; ++z) {
        const unsigned* p = pr + z * 6;
        for (int e = 0; e < 6; ++e) {
            unsigned long long v = ((unsigned long long)p[e] << 3) | (unsigned)z;
            if (v >= best[7]) break;      // sublist ascending
            best[7] = v;
#pragma unroll
            for (int k = 6; k >= 0; --k) {
                if (best[k + 1] < best[k]) {
                    unsigned long long t = best[k]; best[k] = best[k + 1]; best[k + 1] = t;
                }
            }
        }
    }

    const int base = i & ~(NN - 1);
    // query row in registers
    float4 qv[C / 4];
    const float4* qp = (const float4*)(x + (size_t)i * C);
#pragma unroll
    for (int t = 0; t < C / 4; ++t) qv[t] = qp[t];

    unsigned long long out6[6];
#pragma unroll
    for (int k = 0; k < 6; ++k) out6[k] = ~0ull;

    for (int m = 0; m < 8; ++m) {
        // decode (z, embedded e-bits) -> batch-local candidate index
        const unsigned u32k = (unsigned)(best[m] >> 3);
        const int z = (int)(best[m] & 7ull);
        const unsigned orig = (u32k & 0x80000000u) ? (u32k ^ 0x80000000u) : ~u32k;
        const int e = (int)(orig & 255u);
        const int idx = e & 15;
        const int jloc = (z >> 1) * (NN / 4) + (e >> 4) * 32 +
                         (idx & 3) + 8 * (idx >> 2) + (z & 1) * 4;

        const float4* cp = (const float4*)(x + (size_t)(base + jloc) * C);
        float d0 = 0.f, d1 = 0.f, d2 = 0.f, d3 = 0.f;
#pragma unroll
        for (int t = 0; t < C / 4; ++t) {
            float4 a = cp[t];
            d0 = fmaf(a.x, qv[t].x, d0);
            d1 = fmaf(a.y, qv[t].y, d1);
            d2 = fmaf(a.z, qv[t].z, d2);
            d3 = fmaf(a.w, qv[t].w, d3);
        }
        const float s = fmaf(-2.f, (d0 + d1) + (d2 + d3), sqv[base + jloc]);
        unsigned u = __float_as_uint(s);
        u ^= (u & 0x80000000u) ? 0xFFFFFFFFu : 0x80000000u;
        unsigned long long key = ((unsigned long long)u << 11) | (unsigned)jloc;
#pragma unroll
        for (int k = 0; k < 6; ++k) {
            const unsigned long long ok = out6[k];
            const bool c = key < ok;
            out6[k] = c ? key : ok;
            key     = c ? ok  : key;
        }
    }
#pragma unroll
    for (int k = 0; k < 6; ++k)
        nbr[i * KNB + k] = base + (int)(out6[k] & 2047ull);
}

// ---------------- edge MLP kernel ----------------
template<int CIN, int COUT, bool RESID, int MINW>
__global__ __launch_bounds__(384, MINW)
void mlp_kernel(const float* __restrict__ xin, const int* __restrict__ nbr,
                const float* __restrict__ W1T, const float* __restrict__ b1,
                const float* __restrict__ W2,  const float* __restrict__ b2,
                const float* __restrict__ resid, float* __restrict__ out) {
    constexpr int RS = COUT + 4;
    __shared__ float Buf[3][64][RS];

    const int lane = threadIdx.x & 63;
    const int w    = __builtin_amdgcn_readfirstlane(threadIdx.x >> 6);  // 0..5
    const int i    = blockIdx.x * 64 + lane;

    float xi[CIN], xd[CIN];
    {
        const float* xp = xin + (size_t)i * CIN;
#pragma unroll
        for (int c = 0; c < CIN; c += 4) {
            float4 f = *(const float4*)(xp + c);
            xi[c] = f.x; xi[c + 1] = f.y; xi[c + 2] = f.z; xi[c + 3] = f.w;
        }
        const int j = nbr[i * KNB + w];
        const float* jp = xin + (size_t)j * CIN;
#pragma unroll
        for (int c = 0; c < CIN; c += 4) {
            float4 f = *(const float4*)(jp + c);
            xd[c]     = f.x - xi[c];     xd[c + 1] = f.y - xi[c + 1];
            xd[c + 2] = f.z - xi[c + 2]; xd[c + 3] = f.w - xi[c + 3];
        }
    }

    float uacc[COUT];
#pragma unroll
    for (int o = 0; o < COUT; ++o) uacc[o] = 0.f;

    cfloat* W1c = (cfloat*)(uintptr_t)W1T;
    cfloat* b1c = (cfloat*)(uintptr_t)b1;
    cfloat* W2c = (cfloat*)(uintptr_t)W2;

    for (int op = 0; op < COUT; ++op) {
        cfloat* w1r = W1c + (size_t)op * (2 * CIN);
        float h0 = 0.f, h1 = 0.f, h2 = 0.f, h3 = 0.f;
#pragma unroll
        for (int c = 0; c < CIN; c += 4) {
            h0 = fmaf(w1r[c],     xi[c],     h0);
            h1 = fmaf(w1r[c + 1], xi[c + 1], h1);
            h2 = fmaf(w1r[c + 2], xi[c + 2], h2);
            h3 = fmaf(w1r[c + 3], xi[c + 3], h3);
        }
#pragma unroll
        for (int c = 0; c < CIN; c += 4) {
            h0 = fmaf(w1r[CIN + c],     xd[c],     h0);
            h1 = fmaf(w1r[CIN + c + 1], xd[c + 1], h1);
            h2 = fmaf(w1r[CIN + c + 2], xd[c + 2], h2);
            h3 = fmaf(w1r[CIN + c + 3], xd[c + 3], h3);
        }
        const float h = fmaxf((h0 + h1) + (h2 + h3) + b1c[op], 0.f);
        cfloat* w2r = W2c + (size_t)op * COUT;
#pragma unroll
        for (int o = 0; o < COUT; ++o)
            uacc[o] = fmaf(w2r[o], h, uacc[o]);
    }

    if (w >= 3) {
#pragma unroll
        for (int o = 0; o < COUT; ++o) Buf[w - 3][lane][o] = uacc[o];
    }
    __syncthreads();
    if (w < 3) {
#pragma unroll
        for (int o = 0; o < COUT; ++o) uacc[o] = fmaxf(uacc[o], Buf[w][lane][o]);
    }
    __syncthreads();
    if (w == 1 || w == 2) {
#pragma unroll
        for (int o = 0; o < COUT; ++o) Buf[w][lane][o] = uacc[o];
    }
    __syncthreads();
    if (w == 0) {
        float* po = out + (size_t)i * COUT;
#pragma unroll
        for (int o = 0; o < COUT; ++o) {
            float v = fmaxf(uacc[o], fmaxf(Buf[1][lane][o], Buf[2][lane][o])) + b2[o];
            if (RESID) v += resid[(size_t)i * COUT + o];
            po[o] = fmaxf(v, 0.f);
        }
    }
}

extern "C" void kernel_launch(void* const* d_in, const int* in_sizes, int n_in,
                              void* d_out, int out_size, void* d_ws, size_t ws_size,
                              hipStream_t stream) {
    const float* x    = (const float*)d_in[0];
    const float* W1_0 = (const float*)d_in[2];
    const float* b1_0 = (const float*)d_in[3];
    const float* W2_0 = (const float*)d_in[4];
    const float* b2_0 = (const float*)d_in[5];
    const float* W1_1 = (const float*)d_in[6];
    const float* b1_1 = (const float*)d_in[7];
    const float* W2_1 = (const float*)d_in[8];
    const float* b2_1 = (const float*)d_in[9];
    const float* W1_2 = (const float*)d_in[10];
    const float* b1_2 = (const float*)d_in[11];
    const float* W2_2 = (const float*)d_in[12];
    const float* b2_2 = (const float*)d_in[13];
    float* outp = (float*)d_out;

    // workspace layout
    unsigned* plist = (unsigned*)d_ws;                            // NPTS*48 u32
    float* x0  = (float*)(plist + (size_t)NPTS * 48);             // 32768 x 64
    float* x1  = x0 + (size_t)NPTS * 64;                          // 32768 x 32
    float* sqb = x1 + (size_t)NPTS * 32;                          // 32768
    float* T0  = sqb + NPTS;                                      // 64 x 64
    float* T1  = T0 + 4096;                                       // 32 x 128
    float* T2  = T1 + 4096;                                       // 64 x 64
    unsigned short* Xhi = (unsigned short*)(T2 + 4096);           // 32768 x 64 u16
    unsigned short* Xlo = Xhi + (size_t)NPTS * 64;                // 32768 x 64 u16
    int* nbr = (int*)(Xlo + (size_t)NPTS * 64);                   // 32768 x 6

    const int sgrid  = NPTS / 256;
    const int scgrid = 1024;            // 4096 waves of 32q x 512c
    const int pgrid  = NPTS / 64;

    prep_w<<<16, 256, 0, stream>>>(W1_0, W1_1, W1_2, T0, T1, T2);

    // ---- layer 0: x (32) -> x0 (64), relu ----
    prep_fused<32><<<sgrid, 256, 0, stream>>>(x, Xhi, Xlo, sqb);
    knn_scan<32, 4><<<scgrid, 256, 0, stream>>>(Xhi, Xlo, sqb, plist);
    rescore<32><<<sgrid, 256, 0, stream>>>(x, sqb, plist, nbr);
    mlp_kernel<32, 64, false, 3><<<pgrid, 384, 0, stream>>>(x, nbr, T0, b1_0, W2_0, b2_0, nullptr, x0);

    // ---- layer 1: x0 (64) -> x1 (32), relu ----
    prep_fused<64><<<sgrid, 256, 0, stream>>>(x0, Xhi, Xlo, sqb);
    knn_scan<64, 3><<<scgrid, 256, 0, stream>>>(Xhi, Xlo, sqb, plist);
    rescore<64><<<sgrid, 256, 0, stream>>>(x0, sqb, plist, nbr);
    mlp_kernel<64, 32, false, 2><<<pgrid, 384, 0, stream>>>(x0, nbr, T1, b1_1, W2_1, b2_1, nullptr, x1);

    // ---- layer 2: x1 (32) -> out (64), +x0 residual, relu ----
    prep_fused<32><<<sgrid, 256, 0, stream>>>(x1, Xhi, Xlo, sqb);
    knn_scan<32, 4><<<scgrid, 256, 0, stream>>>(Xhi, Xlo, sqb, plist);
    rescore<32><<<sgrid, 256, 0, stream>>>(x1, sqb, plist, nbr);
    mlp_kernel<32, 64, true, 3><<<pgrid, 384, 0, stream>>>(x1, nbr, T2, b1_2, W2_2, b2_2, x0, outp);
}